// Round 1
// baseline (155.649 us; speedup 1.0000x reference)
//
#include <hip/hip_runtime.h>

// CorpusSupportSets, round 4: fuse K1 (one-hot scan) + K2 (compute) into a
// single wave-per-sample kernel.
//  - removes the idx HBM round-trip and the K1->K2 graph serialization
//  - removes one kernel launch
//  - z loads are issued BEFORE the mask scan so their HBM latency overlaps
//    the dependent scan chain
//  - found-index broadcast via ballot+ffs+1 shuffle (was 6 shuffle rounds)
//  - k readfirstlane'd to SGPR so alphas/loggamma become scalar loads

constexpr int K   = 1000;
constexpr int DIM = 768;
constexpr int VPR = K / 4;   // float4 vectors per mask row = 250

typedef float f4 __attribute__((ext_vector_type(4)));  // native vec4

__global__ __launch_bounds__(256) void css_fused_kernel(
    const f4*    __restrict__ mask4,
    const float* __restrict__ z,
    const float* __restrict__ ss,
    const float* __restrict__ alphas,
    const float* __restrict__ loggamma,
    float*       __restrict__ out,
    int bs)
{
    const int b    = (blockIdx.x * blockDim.x + threadIdx.x) >> 6;  // wave/sample
    const int lane = threadIdx.x & 63;
    if (b >= bs) return;

    // Independent z loads first — overlap the mask-scan latency chain.
    const f4* zrow = (const f4*)(z + (size_t)b * DIM);
    f4 z4[3];
    #pragma unroll
    for (int i = 0; i < 3; ++i)
        z4[i] = __builtin_nontemporal_load(zrow + lane + i * 64);

    // Wave-cooperative one-hot scan with early exit (expected ~62.5% of row).
    const f4* mrow = mask4 + (size_t)b * VPR;
    int found = -1;
    #pragma unroll 1
    for (int i = 0; i < 4; ++i) {
        const int e = i * 64 + lane;
        if (e < VPR) {
            f4 v = __builtin_nontemporal_load(mrow + e);
            if (v.x != 0.f) found = e * 4 + 0;
            if (v.y != 0.f) found = e * 4 + 1;
            if (v.z != 0.f) found = e * 4 + 2;
            if (v.w != 0.f) found = e * 4 + 3;
        }
        // wave-uniform early exit: one-hot guarantees at most one lane hits
        if (__ballot(found >= 0)) break;
    }
    // Broadcast the hit lane's index: ballot + ffs + one shuffle.
    const unsigned long long hit = __ballot(found >= 0);
    int k = 0;
    if (hit) k = __shfl(found, (int)__ffsll(hit) - 1, 64);
    k = (k < 0) ? 0 : (k >= K ? K - 1 : k);    // all-zero-row / poison defence
    k = __builtin_amdgcn_readfirstlane(k);     // wave-uniform -> SGPR

    const float a0  = alphas[2 * k];
    const float a1  = alphas[2 * k + 1];
    const float lg0 = loggamma[2 * k];
    const float lg1 = loggamma[2 * k + 1];

    const f4* srow = (const f4*)(ss + (size_t)k * (2 * DIM));

    f4 d0[3], d1[3];
    // 6 independent partials, reduced in ONE butterfly round:
    float sqn0 = 0.f, sqn1 = 0.f, zd0 = 0.f, zd1 = 0.f, d01 = 0.f, zsq = 0.f;
    #pragma unroll
    for (int i = 0; i < 3; ++i) {
        f4 s0 = srow[lane + i * 64];          // cached: rows reused ~16x
        f4 s1 = srow[192 + lane + i * 64];
        d0[i] = z4[i] - s0;
        d1[i] = z4[i] - s1;
        sqn0 += d0[i].x*d0[i].x + d0[i].y*d0[i].y + d0[i].z*d0[i].z + d0[i].w*d0[i].w;
        sqn1 += d1[i].x*d1[i].x + d1[i].y*d1[i].y + d1[i].z*d1[i].z + d1[i].w*d1[i].w;
        zd0  += z4[i].x*d0[i].x + z4[i].y*d0[i].y + z4[i].z*d0[i].z + z4[i].w*d0[i].w;
        zd1  += z4[i].x*d1[i].x + z4[i].y*d1[i].y + z4[i].z*d1[i].z + z4[i].w*d1[i].w;
        d01  += d0[i].x*d1[i].x + d0[i].y*d1[i].y + d0[i].z*d1[i].z + d0[i].w*d1[i].w;
        zsq  += z4[i].x*z4[i].x + z4[i].y*z4[i].y + z4[i].z*z4[i].z + z4[i].w*z4[i].w;
    }
    #pragma unroll
    for (int off = 1; off < 64; off <<= 1) {
        sqn0 += __shfl_xor(sqn0, off, 64);
        sqn1 += __shfl_xor(sqn1, off, 64);
        zd0  += __shfl_xor(zd0,  off, 64);
        zd1  += __shfl_xor(zd1,  off, 64);
        d01  += __shfl_xor(d01,  off, 64);
        zsq  += __shfl_xor(zsq,  off, 64);
    }

    const float g0 = expf(lg0);
    const float g1 = expf(lg1);
    const float c0 = -2.f * a0 * g0 * expf(-g0 * sqn0);
    const float c1 = -2.f * a1 * g1 * expf(-g1 * sqn1);
    const float dot    = c0 * zd0 + c1 * zd1;                       // z . grad
    const float gradsq = c0*c0*sqn0 + 2.f*c0*c1*d01 + c1*c1*sqn1;   // ||grad||^2
    const float nsq    = gradsq - 2.f*dot*dot + dot*dot*zsq;        // ||proj||^2
    const float inv    = 1.f / sqrtf(nsq);

    f4* orow = (f4*)(out + (size_t)b * DIM);
    #pragma unroll
    for (int i = 0; i < 3; ++i) {
        f4 r = (c0 * d0[i] + c1 * d1[i] - dot * z4[i]) * inv;
        __builtin_nontemporal_store(r, orow + lane + i * 64);
    }
}

extern "C" void kernel_launch(void* const* d_in, const int* in_sizes, int n_in,
                              void* d_out, int out_size, void* d_ws, size_t ws_size,
                              hipStream_t stream) {
    const float* mask     = (const float*)d_in[0];
    const float* z        = (const float*)d_in[1];
    const float* ss       = (const float*)d_in[2];
    const float* alphas   = (const float*)d_in[3];
    const float* loggamma = (const float*)d_in[4];
    float* out = (float*)d_out;

    const int bs = in_sizes[1] / DIM;            // 16384

    // one wave per sample, 4 samples per block
    const int blocks = (bs + 3) / 4;
    css_fused_kernel<<<blocks, 256, 0, stream>>>(
        (const f4*)mask, z, ss, alphas, loggamma, out, bs);
}